// Round 17
// baseline (598.991 us; speedup 1.0000x reference)
//
#include <hip/hip_runtime.h>
#include <cstdint>
#include <cstddef>

#define B_GRAPHS 2048
#define N_NODES  64
#define FIN      49
#define D_DIM    256
#define H_HEADS  8
#define DK_DIM   32
#define L_LAYERS 6
#define ALPHA    0.2f
#define LOG2E    1.4426950408889634f

#define M_FULL     (B_GRAPHS * N_NODES)           // 131072 rows
#define WROWS      272                             // 256 W rows + 16 Wa rows
#define WSLAB      (WROWS * 256)                   // per-layer weight slab elems

typedef __bf16 bf16x8 __attribute__((ext_vector_type(8)));
typedef __bf16 bf16x4 __attribute__((ext_vector_type(4)));
typedef float  f32x4  __attribute__((ext_vector_type(4)));

#define MFMA16(a, b, c) __builtin_amdgcn_mfma_f32_16x16x32_bf16(a, b, c, 0, 0, 0)

__device__ __forceinline__ float leaky(float t) { return t > 0.f ? t : ALPHA * t; }

// LDS map (53776 B -> 54272 alloc). Register file (not LDS) caps occupancy
// at 2 waves/SIMD (R16 experiment), so accE AGPRs are free.
#define LDS_H     0        // h tile [64][256] bf16 swizzled, 32768 B
#define LDS_V     32768    // V per wave 4096 B (x4); aliased by xb stage + pool
#define LDS_E     49152    // E per wave 1024 B (x4)
#define LDS_AM    53248    // adjacency masks u64[64] = 512
#define LDS_VALID 53760    // valid bitmask u64 + invcnt f32
#define LDS_TOTAL 53776

// ---------------------------------------------------------------------------
// Weight prep: W + appended Wa = W^T a rows -> single bf16; ba = a.b (f32).
//   Wb: [6][272][256]; rows 0..255 = W[n][k], rows 256..271 = Wa[c][k],
//   c = 2h+sd.  ba: [6][16].
// ---------------------------------------------------------------------------
__global__ void convert_weights(const float* __restrict__ W_emb,
                                const float* __restrict__ gat_W,
                                const float* __restrict__ gat_a,
                                const float* __restrict__ gat_b,
                                __bf16* __restrict__ Wemb_b,   // [256][64]
                                __bf16* __restrict__ Wb,       // [6][272][256]
                                float* __restrict__ ba)        // [6][16]
{
    int idx = blockIdx.x * 256 + threadIdx.x;
    if (idx < 256 * 64) {
        int n = idx >> 6, k = idx & 63;
        float f = (k < FIN) ? W_emb[n * FIN + k] : 0.f;
        Wemb_b[idx] = (__bf16)f;
    }
    if (idx < L_LAYERS * 65536) {
        int l = idx >> 16, nk = idx & 65535;
        Wb[l * WSLAB + nk] = (__bf16)gat_W[idx];
    }
    int o = idx - L_LAYERS * 65536;
    if (o >= 0 && o < L_LAYERS * 4096) {
        int l = o >> 12, r = o & 4095;
        int k = r >> 4, c = r & 15;
        int hh = c >> 1, sd = c & 1;
        const float* av = gat_a + l * 512 + hh * 64 + sd * 32;
        const float* wp = gat_W + ((size_t)l * 256 + hh * 32) * 256 + k;
        float s = 0.f;
        for (int d = 0; d < 32; d++) s += av[d] * wp[d * 256];
        Wb[l * WSLAB + (256 + c) * 256 + k] = (__bf16)s;
    }
    int o2 = idx - L_LAYERS * 65536 - L_LAYERS * 4096;
    if (o2 >= 0 && o2 < L_LAYERS * 16) {
        int l = o2 >> 4, c = o2 & 15;
        int hh = c >> 1, sd = c & 1;
        const float* av = gat_a + l * 512 + hh * 64 + sd * 32;
        const float* bp = gat_b + l * 256 + hh * 32;
        float s = 0.f;
        for (int d = 0; d < 32; d++) s += av[d] * bp[d];
        ba[o2] = s;
    }
}

// x [M][49] fp32 -> xb [M][64] bf16 (zero-padded)
__global__ void convert_x(const float* __restrict__ x, __bf16* __restrict__ xb)
{
    int idx = blockIdx.x * 256 + threadIdx.x;
    int m = idx >> 6, k = idx & 63;
    xb[idx] = (__bf16)((k < FIN) ? x[m * FIN + k] : 0.f);
}

// ---------------------------------------------------------------------------
// MEGA kernel: one block per graph runs the ENTIRE network. This round:
// es/ed moved OFF the VALU (512+ shfl/fma ops per thread per layer) onto the
// matrix pipe via appended Wa weight rows -> accE (16 AGPRs, free at our
// register-bound 2 waves/SIMD). E rows written once per layer from accE.
// History: (256,4)->64-reg spill (R6); 3-term reg-dbuf spill (R8);
// TLP doesn't fix per-wave latency (R10); h staged once (R11); full fusion
// -> HBM~0 (R12); runtime-conditional skip broke scheduling (R13); (256,3)
// reg-cap spill (R14); setprio neutral (R15); LDS diet -> register-bound
// confirmed (R16). NEVER force min-waves bounds beyond 2 on this kernel.
// ---------------------------------------------------------------------------
__global__ __launch_bounds__(256, 2)
void mega_gat(const float* __restrict__ A,
              const __bf16* __restrict__ xb,
              const __bf16* __restrict__ Wemb,
              const __bf16* __restrict__ Wb_all,
              const float* __restrict__ gat_b_all,
              const float* __restrict__ ba_all,
              const float* __restrict__ W1, const float* __restrict__ b1,
              const float* __restrict__ W2, const float* __restrict__ b2,
              const float* __restrict__ W3, const float* __restrict__ b3,
              float* __restrict__ out)
{
    __shared__ __align__(16) char smem[LDS_TOTAL];

    const int tid  = threadIdx.x;
    const int lane = tid & 63;
    const int w    = tid >> 6;
    const int q    = lane >> 4;
    const int d15  = lane & 15;
    const int g    = blockIdx.x;

    char*  vwbase = smem + LDS_V + w * 4096;
    float* E      = (float*)(smem + LDS_E + w * 1024);
    unsigned long long* Am = (unsigned long long*)(smem + LDS_AM);

    auto h_off = [&](int i, int d) -> int {
        return i * 512 + ((((d >> 3) ^ (i & 7)) << 4)) + ((d & 7) << 1);
    };

    // ---------------- staging (one latency window) ----------------
    {   // xb tile [64][64] bf16 -> V area, swizzled
        const char* src = (const char*)(xb + (size_t)g * 4096);
        bf16x8 t0 = *(const bf16x8*)(src + tid * 16);
        bf16x8 t1 = *(const bf16x8*)(src + 4096 + tid * 16);
        int u0 = tid, u1 = 256 + tid;
        int r0 = u0 >> 3, s0 = u0 & 7;
        int r1 = u1 >> 3, s1 = u1 & 7;
        *(bf16x8*)(smem + LDS_V + r0 * 128 + ((s0 ^ (r0 & 7)) << 4)) = t0;
        *(bf16x8*)(smem + LDS_V + r1 * 128 + ((s1 ^ (r1 & 7)) << 4)) = t1;
    }
    {   // adjacency bitmasks via ballot
        const float* Ab = A + (size_t)g * 4096;
#pragma unroll
        for (int rr = 0; rr < 16; rr++) {
            int r = w * 16 + rr;
            unsigned long long m = __ballot(Ab[r * 64 + lane] > 0.f);
            if (lane == 0) Am[r] = m;
        }
    }
    __syncthreads();

    // valid-node mask (wave 0; consumed after the embed barrier)
    if (w == 0) {
        unsigned long long rowm = Am[lane];
        unsigned long long vmw = __ballot((rowm >> lane) & 1ULL);
        if (lane == 0) {
            *(unsigned long long*)(smem + LDS_VALID) = vmw;
            *(float*)(smem + LDS_VALID + 8) = 1.f / (float)__popcll(vmw);
        }
    }

    // ---------------- embed GEMM: h = bf16(x @ Wemb^T) ----------------
    {
        f32x4 acc[4][4];
#pragma unroll
        for (int i = 0; i < 4; i++)
#pragma unroll
            for (int j = 0; j < 4; j++) acc[i][j] = (f32x4){0.f, 0.f, 0.f, 0.f};
#pragma unroll
        for (int ks = 0; ks < 2; ks++) {
            const int k0 = ks * 32 + q * 8;
            const int sl = ks * 4 + q;
            bf16x8 ah[4];
#pragma unroll
            for (int mf = 0; mf < 4; mf++) {
                int r = mf * 16 + d15;
                ah[mf] = *(const bf16x8*)(smem + LDS_V + r * 128 + ((sl ^ (r & 7)) << 4));
            }
#pragma unroll
            for (int nf = 0; nf < 4; nf++) {
                bf16x8 bh = *(const bf16x8*)(Wemb + (size_t)(w * 64 + nf * 16 + d15) * 64 + k0);
#pragma unroll
                for (int mf = 0; mf < 4; mf++)
                    acc[mf][nf] = MFMA16(ah[mf], bh, acc[mf][nf]);
            }
        }
#pragma unroll
        for (int nf = 0; nf < 4; nf++) {
            int d = w * 64 + nf * 16 + d15;
#pragma unroll
            for (int mf = 0; mf < 4; mf++)
#pragma unroll
                for (int rr = 0; rr < 4; rr++) {
                    int i = mf * 16 + q * 4 + rr;
                    *(__bf16*)(smem + h_off(i, d)) = (__bf16)acc[mf][nf][rr];
                }
        }
    }
    __syncthreads();   // h-tile complete; xb stage dead; vm visible

    const unsigned long long vm = *(const unsigned long long*)(smem + LDS_VALID);

    // ---------------- 6 GAT layers, h resident in LDS ----------------
#pragma unroll 1
    for (int l = 0; l < L_LAYERS; l++) {
        const __bf16* Wl = Wb_all + (size_t)l * WSLAB;

        float bvreg[4];
#pragma unroll
        for (int nf = 0; nf < 4; nf++)
            bvreg[nf] = gat_b_all[l * 256 + w * 64 + nf * 16 + d15];

        f32x4 acc[4][4], accE[4];
#pragma unroll
        for (int i = 0; i < 4; i++) {
            accE[i] = (f32x4){0.f, 0.f, 0.f, 0.f};
#pragma unroll
            for (int j = 0; j < 4; j++) acc[i][j] = (f32x4){0.f, 0.f, 0.f, 0.f};
        }

        bf16x8 breg[3][5];
        auto loadB = [&](int buf, int ks) {
            const int k0 = ks * 32 + q * 8;
#pragma unroll
            for (int nt = 0; nt < 5; nt++) {
                int n = (nt < 4) ? (w * 64 + nt * 16 + d15) : (256 + d15);
                breg[buf][nt] = *(const bf16x8*)(Wl + (size_t)n * 256 + k0);
            }
        };
        loadB(0, 0);
        loadB(1, 1);

#pragma unroll
        for (int ks = 0; ks < 8; ks++) {
            if (ks + 2 < 8) loadB((ks + 2) % 3, ks + 2);
            bf16x8 ah[4];
            const int sl = ks * 4 + q;
#pragma unroll
            for (int mf = 0; mf < 4; mf++) {
                int r = mf * 16 + d15;
                ah[mf] = *(const bf16x8*)(smem + r * 512 + ((sl ^ (r & 7)) << 4));
            }
#pragma unroll
            for (int nt = 0; nt < 5; nt++)
#pragma unroll
                for (int mf = 0; mf < 4; mf++) {
                    f32x4& dst = (nt < 4) ? acc[mf][nt] : accE[mf];
                    dst = MFMA16(ah[mf], breg[ks % 3][nt], dst);
                }
        }

        __syncthreads();   // all h-tile A-reads done before epilogue writes

        unsigned long long msk[4];
#pragma unroll
        for (int mf = 0; mf < 4; mf++) msk[mf] = Am[mf * 16 + d15];

        // E rows 0..3 (cl = hl*2+sd) from accE: lane holds col c=d15 of the
        // 16 global E-cols; this wave owns c in [4w, 4w+4). Pre-scaled log2e.
        if (d15 >= 4 * w && d15 < 4 * w + 4) {
            const int cl = d15 - 4 * w;
            const float bac = ba_all[l * 16 + 4 * w + cl];
#pragma unroll
            for (int mf = 0; mf < 4; mf++)
#pragma unroll
                for (int rr = 0; rr < 4; rr++)
                    E[cl * 64 + mf * 16 + q * 4 + rr] =
                        (accE[mf][rr] + bac) * LOG2E;
        }

#pragma unroll
        for (int hl = 0; hl < 2; hl++) {
            const int head = 2 * w + hl;

            // V fragments (wave-private, swizzled [d][j] bf16)
#pragma unroll
            for (int nfl = 0; nfl < 2; nfl++) {
                const int nf = hl * 2 + nfl;
                const int d  = nfl * 16 + d15;
                const float bv = bvreg[nf];
                char* vb = vwbase + d * 128;
#pragma unroll
                for (int mf = 0; mf < 4; mf++) {
                    int s   = mf * 2 + (q >> 1);
                    int off = ((s ^ (d & 7)) << 4) + (q & 1) * 8;
                    bf16x4 h4;
#pragma unroll
                    for (int rr = 0; rr < 4; rr++)
                        h4[rr] = (__bf16)(acc[mf][nf][rr] + bv);
                    *(bf16x4*)(vb + off) = h4;
                }
            }

            float ev = E[(hl * 2 + 1) * 64 + lane];
#pragma unroll
            for (int off = 32; off; off >>= 1) ev = fmaxf(ev, __shfl_xor(ev, off));

            float esi[4], mh[4];
#pragma unroll
            for (int mf = 0; mf < 4; mf++) {
                esi[mf] = E[(hl * 2) * 64 + mf * 16 + d15];
                mh[mf]  = leaky(esi[mf] + ev);
            }

            f32x4 pv[4][2];
#pragma unroll
            for (int mf = 0; mf < 4; mf++) {
                pv[mf][0] = (f32x4){0.f, 0.f, 0.f, 0.f};
                pv[mf][1] = (f32x4){0.f, 0.f, 0.f, 0.f};
            }
            float rs[4] = {0.f, 0.f, 0.f, 0.f};

#pragma unroll
            for (int ksj = 0; ksj < 2; ksj++) {
                const int j8 = ksj * 32 + q * 8;
                const int s  = ksj * 4 + q;
                bf16x8 vh[2];
#pragma unroll
                for (int nf2 = 0; nf2 < 2; nf2++) {
                    int d = nf2 * 16 + d15;
                    vh[nf2] = *(const bf16x8*)(vwbase + d * 128 + ((s ^ (d & 7)) << 4));
                }
                float edv[8];
#pragma unroll
                for (int e = 0; e < 8; e++) edv[e] = E[(hl * 2 + 1) * 64 + j8 + e];

#pragma unroll
                for (int mf = 0; mf < 4; mf++) {
                    unsigned int mb = (unsigned int)(msk[mf] >> j8) & 0xffu;
                    bf16x8 ph;
                    float rsum = 0.f;
#pragma unroll
                    for (int e = 0; e < 8; e++) {
                        float t = leaky(esi[mf] + edv[e]);   // log2-scaled
                        float p = ((mb >> e) & 1u)
                                    ? __builtin_amdgcn_exp2f(t - mh[mf]) : 0.f;
                        rsum += p;
                        ph[e] = (__bf16)p;
                    }
                    rs[mf] += rsum;
#pragma unroll
                    for (int nf2 = 0; nf2 < 2; nf2++)
                        pv[mf][nf2] = MFMA16(ph, vh[nf2], pv[mf][nf2]);
                }
            }

            // row sums -> 1/s, parked in the now-dead esi E-row (wave-private)
#pragma unroll
            for (int mf = 0; mf < 4; mf++) {
                float r = rs[mf];
                r += __shfl_xor(r, 16);
                r += __shfl_xor(r, 32);
                if (q == 0)
                    E[(hl * 2) * 64 + mf * 16 + d15] = (r > 0.f) ? 1.f / r : 0.f;
            }

            // epilogue: scale, residual (LDS), ELU, write back to LDS h-tile
#pragma unroll
            for (int mf = 0; mf < 4; mf++) {
#pragma unroll
                for (int nf2 = 0; nf2 < 2; nf2++) {
                    int d = head * 32 + nf2 * 16 + d15;
#pragma unroll
                    for (int rr = 0; rr < 4; rr++) {
                        int i = mf * 16 + q * 4 + rr;
                        float inv = E[(hl * 2) * 64 + i];
                        int hoff = h_off(i, d);
                        float old = (float)*(const __bf16*)(smem + hoff);
                        float o = pv[mf][nf2][rr] * inv + old;
                        o = o > 0.f ? o : __expf(o) - 1.f;
                        *(__bf16*)(smem + hoff) = (__bf16)o;
                    }
                }
            }
        }
        __syncthreads();   // epilogue writes visible to next layer's GEMM
    }

    // ---------------- masked mean pool + MLP ----------------
    {
        float invc = *(const float*)(smem + LDS_VALID + 8);
        float gsum = 0.f;
#pragma unroll 8
        for (int n = 0; n < 64; n++)
            if ((vm >> n) & 1ULL)
                gsum += (float)*(const __bf16*)(smem + h_off(n, tid));

        float* gl = (float*)(smem + LDS_V);          // V area dead now
        float* z1 = (float*)(smem + LDS_V + 1024);
        float* z2 = (float*)(smem + LDS_V + 1536);
        gl[tid] = gsum * invc;
        __syncthreads();

        if (tid < 128) {
            const float* wr = W1 + tid * 256;
            float z = 0.f;
#pragma unroll 8
            for (int k = 0; k < 256; k += 4) {
                float4 wv = *(const float4*)&wr[k];
                z += wv.x * gl[k] + wv.y * gl[k + 1] + wv.z * gl[k + 2] + wv.w * gl[k + 3];
            }
            z += b1[tid];
            z1[tid] = z > 0.f ? z : 0.f;
        }
        __syncthreads();

        if (tid < 128) {
            const float* wr = W2 + tid * 128;
            float z = 0.f;
#pragma unroll 8
            for (int k = 0; k < 128; k += 4) {
                float4 wv = *(const float4*)&wr[k];
                z += wv.x * z1[k] + wv.y * z1[k + 1] + wv.z * z1[k + 2] + wv.w * z1[k + 3];
            }
            z += b2[tid];
            z2[tid] = z > 0.f ? z : 0.f;
        }
        __syncthreads();

        if (tid < 64) {
            float p = W3[tid] * z2[tid] + W3[tid + 64] * z2[tid + 64];
#pragma unroll
            for (int off = 32; off; off >>= 1) p += __shfl_down(p, off);
            if (tid == 0) {
                float z = p + b3[0];
                out[g] = (z > 0.f ? z : __expf(z) - 1.f) + 1.5f;
            }
        }
    }
}

// ---------------------------------------------------------------------------
extern "C" void kernel_launch(void* const* d_in, const int* in_sizes, int n_in,
                              void* d_out, int out_size, void* d_ws, size_t ws_size,
                              hipStream_t stream)
{
    const float* x      = (const float*)d_in[0];
    const float* A      = (const float*)d_in[1];
    const float* W_emb  = (const float*)d_in[2];
    const float* gat_W  = (const float*)d_in[3];
    const float* gat_b  = (const float*)d_in[4];
    const float* gat_a  = (const float*)d_in[5];
    const float* fc_W1  = (const float*)d_in[6];
    const float* fc_b1  = (const float*)d_in[7];
    const float* fc_W2  = (const float*)d_in[8];
    const float* fc_b2  = (const float*)d_in[9];
    const float* fc_W3  = (const float*)d_in[10];
    const float* fc_b3  = (const float*)d_in[11];
    float* out = (float*)d_out;

    // workspace (~17.7 MB):
    //   xb bf16 [131072][64]   @ 0          16777216
    //   Wemb_b [256][64]       @ 16777216   32768
    //   Wb [6][272][256] bf16  @ 16809984   835584
    //   ba [6][16] f32         @ 17645568   384
    char* ws = (char*)d_ws;
    __bf16* xb     = (__bf16*)ws;
    __bf16* Wemb_b = (__bf16*)(ws + 16777216);
    __bf16* Wb     = (__bf16*)(ws + 16809984);
    float*  ba     = (float*)(ws + 17645568);

    int conv_total = L_LAYERS * 65536 + L_LAYERS * 4096 + L_LAYERS * 16;
    convert_weights<<<(conv_total + 255) / 256, 256, 0, stream>>>(
        W_emb, gat_W, gat_a, gat_b, Wemb_b, Wb, ba);
    convert_x<<<M_FULL * 64 / 256, 256, 0, stream>>>(x, xb);

    mega_gat<<<B_GRAPHS, 256, 0, stream>>>(
        A, xb, Wemb_b, Wb, gat_b, ba,
        fc_W1, fc_b1, fc_W2, fc_b2, fc_W3, fc_b3, out);
}

// Round 18
// 552.628 us; speedup vs baseline: 1.0839x; 1.0839x over previous
//
#include <hip/hip_runtime.h>
#include <cstdint>
#include <cstddef>

#define B_GRAPHS 2048
#define N_NODES  64
#define FIN      49
#define D_DIM    256
#define H_HEADS  8
#define DK_DIM   32
#define L_LAYERS 6
#define ALPHA    0.2f
#define LOG2E    1.4426950408889634f

#define M_FULL     (B_GRAPHS * N_NODES)           // 131072 rows
#define WSLAB      (256 * 256)                     // per-layer weight slab elems

typedef __bf16 bf16x8 __attribute__((ext_vector_type(8)));
typedef __bf16 bf16x4 __attribute__((ext_vector_type(4)));
typedef float  f32x4  __attribute__((ext_vector_type(4)));

#define MFMA16(a, b, c) __builtin_amdgcn_mfma_f32_16x16x32_bf16(a, b, c, 0, 0, 0)

__device__ __forceinline__ float leaky(float t) { return t > 0.f ? t : ALPHA * t; }

// LDS map (53776 B -> 54272 alloc). Register file (not LDS) caps occupancy
// at 2 waves/SIMD (R16 experiment). R16 config = verified best (554 us).
#define LDS_H     0        // h tile [64][256] bf16 swizzled, 32768 B
#define LDS_V     32768    // V per wave 4096 B (x4); aliased by xb stage + pool
#define LDS_E     49152    // E per wave 1024 B (x4)
#define LDS_AM    53248    // adjacency masks u64[64] = 512
#define LDS_VALID 53760    // valid bitmask u64 + invcnt f32
#define LDS_TOTAL 53776

// ---------------------------------------------------------------------------
// Weight prep: W -> single bf16; ba[l][c] = a[l,h,sd*32:] . b[l,h*32:] (f32).
// ---------------------------------------------------------------------------
__global__ void convert_weights(const float* __restrict__ W_emb,
                                const float* __restrict__ gat_W,
                                const float* __restrict__ gat_a,
                                const float* __restrict__ gat_b,
                                __bf16* __restrict__ Wemb_b,   // [256][64]
                                __bf16* __restrict__ Wb,       // [6][256][256]
                                float* __restrict__ ba)        // [6][16]
{
    int idx = blockIdx.x * 256 + threadIdx.x;
    if (idx < 256 * 64) {
        int n = idx >> 6, k = idx & 63;
        float f = (k < FIN) ? W_emb[n * FIN + k] : 0.f;
        Wemb_b[idx] = (__bf16)f;
    }
    if (idx < L_LAYERS * 65536) {
        Wb[idx] = (__bf16)gat_W[idx];
    }
    int o2 = idx - L_LAYERS * 65536;
    if (o2 >= 0 && o2 < L_LAYERS * 16) {
        int l = o2 >> 4, c = o2 & 15;
        int hh = c >> 1, sd = c & 1;
        const float* av = gat_a + l * 512 + hh * 64 + sd * 32;
        const float* bp = gat_b + l * 256 + hh * 32;
        float s = 0.f;
        for (int d = 0; d < 32; d++) s += av[d] * bp[d];
        ba[o2] = s;
    }
}

// x [M][49] fp32 -> xb [M][64] bf16 (zero-padded)
__global__ void convert_x(const float* __restrict__ x, __bf16* __restrict__ xb)
{
    int idx = blockIdx.x * 256 + threadIdx.x;
    int m = idx >> 6, k = idx & 63;
    xb[idx] = (__bf16)((k < FIN) ? x[m * FIN + k] : 0.f);
}

// ---------------------------------------------------------------------------
// MEGA kernel: one block per graph runs the ENTIRE network (R16 verbatim,
// the verified best: 554 us). Levers tested & closed on this structure:
// (256,4)->64-reg spill (R6); 3-term reg-dbuf spill (R8); TLP doesn't fix
// per-wave latency (R10); h staged once (R11); full fusion -> HBM~0 (R12);
// runtime-conditional skip broke scheduling (R13); (256,3) reg-cap spill
// (R14); setprio neutral (R15); LDS diet -> register-bound confirmed (R16);
// accE VALU-offload -> spill regression (R17). NEVER force min-waves bounds
// beyond 2; do NOT add register-resident pipelining.
// ---------------------------------------------------------------------------
__global__ __launch_bounds__(256, 2)
void mega_gat(const float* __restrict__ A,
              const __bf16* __restrict__ xb,
              const __bf16* __restrict__ Wemb,
              const __bf16* __restrict__ Wb_all,
              const float* __restrict__ gat_b_all,
              const float* __restrict__ a_all,
              const float* __restrict__ ba_all,
              const float* __restrict__ W1, const float* __restrict__ b1,
              const float* __restrict__ W2, const float* __restrict__ b2,
              const float* __restrict__ W3, const float* __restrict__ b3,
              float* __restrict__ out)
{
    __shared__ __align__(16) char smem[LDS_TOTAL];

    const int tid  = threadIdx.x;
    const int lane = tid & 63;
    const int w    = tid >> 6;
    const int q    = lane >> 4;
    const int d15  = lane & 15;
    const int g    = blockIdx.x;

    char*  vwbase = smem + LDS_V + w * 4096;
    float* E      = (float*)(smem + LDS_E + w * 1024);
    unsigned long long* Am = (unsigned long long*)(smem + LDS_AM);

    auto h_off = [&](int i, int d) -> int {
        return i * 512 + ((((d >> 3) ^ (i & 7)) << 4)) + ((d & 7) << 1);
    };

    // ---------------- staging (one latency window) ----------------
    {   // xb tile [64][64] bf16 -> V area, swizzled
        const char* src = (const char*)(xb + (size_t)g * 4096);
        bf16x8 t0 = *(const bf16x8*)(src + tid * 16);
        bf16x8 t1 = *(const bf16x8*)(src + 4096 + tid * 16);
        int u0 = tid, u1 = 256 + tid;
        int r0 = u0 >> 3, s0 = u0 & 7;
        int r1 = u1 >> 3, s1 = u1 & 7;
        *(bf16x8*)(smem + LDS_V + r0 * 128 + ((s0 ^ (r0 & 7)) << 4)) = t0;
        *(bf16x8*)(smem + LDS_V + r1 * 128 + ((s1 ^ (r1 & 7)) << 4)) = t1;
    }
    {   // adjacency bitmasks via ballot
        const float* Ab = A + (size_t)g * 4096;
#pragma unroll
        for (int rr = 0; rr < 16; rr++) {
            int r = w * 16 + rr;
            unsigned long long m = __ballot(Ab[r * 64 + lane] > 0.f);
            if (lane == 0) Am[r] = m;
        }
    }
    __syncthreads();

    // valid-node mask (wave 0; consumed after the embed barrier)
    if (w == 0) {
        unsigned long long rowm = Am[lane];
        unsigned long long vmw = __ballot((rowm >> lane) & 1ULL);
        if (lane == 0) {
            *(unsigned long long*)(smem + LDS_VALID) = vmw;
            *(float*)(smem + LDS_VALID + 8) = 1.f / (float)__popcll(vmw);
        }
    }

    // ---------------- embed GEMM: h = bf16(x @ Wemb^T) ----------------
    {
        f32x4 acc[4][4];
#pragma unroll
        for (int i = 0; i < 4; i++)
#pragma unroll
            for (int j = 0; j < 4; j++) acc[i][j] = (f32x4){0.f, 0.f, 0.f, 0.f};
#pragma unroll
        for (int ks = 0; ks < 2; ks++) {
            const int k0 = ks * 32 + q * 8;
            const int sl = ks * 4 + q;
            bf16x8 ah[4];
#pragma unroll
            for (int mf = 0; mf < 4; mf++) {
                int r = mf * 16 + d15;
                ah[mf] = *(const bf16x8*)(smem + LDS_V + r * 128 + ((sl ^ (r & 7)) << 4));
            }
#pragma unroll
            for (int nf = 0; nf < 4; nf++) {
                bf16x8 bh = *(const bf16x8*)(Wemb + (size_t)(w * 64 + nf * 16 + d15) * 64 + k0);
#pragma unroll
                for (int mf = 0; mf < 4; mf++)
                    acc[mf][nf] = MFMA16(ah[mf], bh, acc[mf][nf]);
            }
        }
#pragma unroll
        for (int nf = 0; nf < 4; nf++) {
            int d = w * 64 + nf * 16 + d15;
#pragma unroll
            for (int mf = 0; mf < 4; mf++)
#pragma unroll
                for (int rr = 0; rr < 4; rr++) {
                    int i = mf * 16 + q * 4 + rr;
                    *(__bf16*)(smem + h_off(i, d)) = (__bf16)acc[mf][nf][rr];
                }
        }
    }
    __syncthreads();   // h-tile complete; xb stage dead; vm visible

    const unsigned long long vm = *(const unsigned long long*)(smem + LDS_VALID);

    // ---------------- 6 GAT layers, h resident in LDS ----------------
#pragma unroll 1
    for (int l = 0; l < L_LAYERS; l++) {
        const __bf16* Wl = Wb_all + (size_t)l * WSLAB;

        // register-prefetch a/bias/ba for this layer (L2-hot; hidden by GEMM)
        float a0r[2][2], a1r[2][2], bar[2][2], bvreg[4];
#pragma unroll
        for (int hp = 0; hp < 2; hp++) {
            const int head = 2 * w + hp;
#pragma unroll
            for (int sd = 0; sd < 2; sd++) {
                a0r[hp][sd] = a_all[l * 512 + head * 64 + sd * 32 + d15];
                a1r[hp][sd] = a_all[l * 512 + head * 64 + sd * 32 + 16 + d15];
                bar[hp][sd] = ba_all[l * 16 + 2 * head + sd];
            }
        }
#pragma unroll
        for (int nf = 0; nf < 4; nf++)
            bvreg[nf] = gat_b_all[l * 256 + w * 64 + nf * 16 + d15];

        f32x4 acc[4][4];
#pragma unroll
        for (int i = 0; i < 4; i++)
#pragma unroll
            for (int j = 0; j < 4; j++) acc[i][j] = (f32x4){0.f, 0.f, 0.f, 0.f};

        bf16x8 breg[3][4];
        auto loadB = [&](int buf, int ks) {
            const int k0 = ks * 32 + q * 8;
#pragma unroll
            for (int nf = 0; nf < 4; nf++)
                breg[buf][nf] = *(const bf16x8*)(Wl + (size_t)(w * 64 + nf * 16 + d15) * 256 + k0);
        };
        loadB(0, 0);
        loadB(1, 1);

#pragma unroll
        for (int ks = 0; ks < 8; ks++) {
            if (ks + 2 < 8) loadB((ks + 2) % 3, ks + 2);
            bf16x8 ah[4];
            const int sl = ks * 4 + q;
#pragma unroll
            for (int mf = 0; mf < 4; mf++) {
                int r = mf * 16 + d15;
                ah[mf] = *(const bf16x8*)(smem + r * 512 + ((sl ^ (r & 7)) << 4));
            }
#pragma unroll
            for (int nf = 0; nf < 4; nf++)
#pragma unroll
                for (int mf = 0; mf < 4; mf++)
                    acc[mf][nf] = MFMA16(ah[mf], breg[ks % 3][nf], acc[mf][nf]);
        }

        __syncthreads();   // all h-tile A-reads done before epilogue writes

        unsigned long long msk[4];
#pragma unroll
        for (int mf = 0; mf < 4; mf++) msk[mf] = Am[mf * 16 + d15];

#pragma unroll
        for (int hl = 0; hl < 2; hl++) {
            const int head = 2 * w + hl;

            // es/ed from acc in-register; E pre-scaled by log2(e)
#pragma unroll
            for (int sd = 0; sd < 2; sd++) {
                float a0 = a0r[hl][sd];
                float a1 = a1r[hl][sd];
                float tmp[4][4];
#pragma unroll
                for (int mf = 0; mf < 4; mf++)
#pragma unroll
                    for (int rr = 0; rr < 4; rr++)
                        tmp[mf][rr] = acc[mf][2 * hl][rr] * a0 + acc[mf][2 * hl + 1][rr] * a1;
#pragma unroll
                for (int off = 1; off <= 8; off <<= 1)
#pragma unroll
                    for (int mf = 0; mf < 4; mf++)
#pragma unroll
                        for (int rr = 0; rr < 4; rr++)
                            tmp[mf][rr] += __shfl_xor(tmp[mf][rr], off);
                float bac = bar[hl][sd];
                if (d15 == 0) {
#pragma unroll
                    for (int mf = 0; mf < 4; mf++)
#pragma unroll
                        for (int rr = 0; rr < 4; rr++)
                            E[(hl * 2 + sd) * 64 + mf * 16 + q * 4 + rr] =
                                (tmp[mf][rr] + bac) * LOG2E;
                }
            }

            // V fragments (wave-private, swizzled [d][j] bf16)
#pragma unroll
            for (int nfl = 0; nfl < 2; nfl++) {
                const int nf = hl * 2 + nfl;
                const int d  = nfl * 16 + d15;
                const float bv = bvreg[nf];
                char* vb = vwbase + d * 128;
#pragma unroll
                for (int mf = 0; mf < 4; mf++) {
                    int s   = mf * 2 + (q >> 1);
                    int off = ((s ^ (d & 7)) << 4) + (q & 1) * 8;
                    bf16x4 h4;
#pragma unroll
                    for (int rr = 0; rr < 4; rr++)
                        h4[rr] = (__bf16)(acc[mf][nf][rr] + bv);
                    *(bf16x4*)(vb + off) = h4;
                }
            }

            float ev = E[(hl * 2 + 1) * 64 + lane];
#pragma unroll
            for (int off = 32; off; off >>= 1) ev = fmaxf(ev, __shfl_xor(ev, off));

            float esi[4], mh[4];
#pragma unroll
            for (int mf = 0; mf < 4; mf++) {
                esi[mf] = E[(hl * 2) * 64 + mf * 16 + d15];
                mh[mf]  = leaky(esi[mf] + ev);
            }

            f32x4 pv[4][2];
#pragma unroll
            for (int mf = 0; mf < 4; mf++) {
                pv[mf][0] = (f32x4){0.f, 0.f, 0.f, 0.f};
                pv[mf][1] = (f32x4){0.f, 0.f, 0.f, 0.f};
            }
            float rs[4] = {0.f, 0.f, 0.f, 0.f};

#pragma unroll
            for (int ksj = 0; ksj < 2; ksj++) {
                const int j8 = ksj * 32 + q * 8;
                const int s  = ksj * 4 + q;
                bf16x8 vh[2];
#pragma unroll
                for (int nf2 = 0; nf2 < 2; nf2++) {
                    int d = nf2 * 16 + d15;
                    vh[nf2] = *(const bf16x8*)(vwbase + d * 128 + ((s ^ (d & 7)) << 4));
                }
                float edv[8];
#pragma unroll
                for (int e = 0; e < 8; e++) edv[e] = E[(hl * 2 + 1) * 64 + j8 + e];

#pragma unroll
                for (int mf = 0; mf < 4; mf++) {
                    unsigned int mb = (unsigned int)(msk[mf] >> j8) & 0xffu;
                    bf16x8 ph;
                    float rsum = 0.f;
#pragma unroll
                    for (int e = 0; e < 8; e++) {
                        float t = leaky(esi[mf] + edv[e]);   // log2-scaled
                        float p = ((mb >> e) & 1u)
                                    ? __builtin_amdgcn_exp2f(t - mh[mf]) : 0.f;
                        rsum += p;
                        ph[e] = (__bf16)p;
                    }
                    rs[mf] += rsum;
#pragma unroll
                    for (int nf2 = 0; nf2 < 2; nf2++)
                        pv[mf][nf2] = MFMA16(ph, vh[nf2], pv[mf][nf2]);
                }
            }

            // row sums -> 1/s, parked in the now-dead esi E-row (wave-private)
#pragma unroll
            for (int mf = 0; mf < 4; mf++) {
                float r = rs[mf];
                r += __shfl_xor(r, 16);
                r += __shfl_xor(r, 32);
                if (q == 0)
                    E[(hl * 2) * 64 + mf * 16 + d15] = (r > 0.f) ? 1.f / r : 0.f;
            }

            // epilogue: scale, residual (LDS), ELU, write back to LDS h-tile
#pragma unroll
            for (int mf = 0; mf < 4; mf++) {
#pragma unroll
                for (int nf2 = 0; nf2 < 2; nf2++) {
                    int d = head * 32 + nf2 * 16 + d15;
#pragma unroll
                    for (int rr = 0; rr < 4; rr++) {
                        int i = mf * 16 + q * 4 + rr;
                        float inv = E[(hl * 2) * 64 + i];
                        int hoff = h_off(i, d);
                        float old = (float)*(const __bf16*)(smem + hoff);
                        float o = pv[mf][nf2][rr] * inv + old;
                        o = o > 0.f ? o : __expf(o) - 1.f;
                        *(__bf16*)(smem + hoff) = (__bf16)o;
                    }
                }
            }
        }
        __syncthreads();   // epilogue writes visible to next layer's GEMM
    }

    // ---------------- masked mean pool + MLP ----------------
    {
        float invc = *(const float*)(smem + LDS_VALID + 8);
        float gsum = 0.f;
#pragma unroll 8
        for (int n = 0; n < 64; n++)
            if ((vm >> n) & 1ULL)
                gsum += (float)*(const __bf16*)(smem + h_off(n, tid));

        float* gl = (float*)(smem + LDS_V);          // V area dead now
        float* z1 = (float*)(smem + LDS_V + 1024);
        float* z2 = (float*)(smem + LDS_V + 1536);
        gl[tid] = gsum * invc;
        __syncthreads();

        if (tid < 128) {
            const float* wr = W1 + tid * 256;
            float z = 0.f;
#pragma unroll 8
            for (int k = 0; k < 256; k += 4) {
                float4 wv = *(const float4*)&wr[k];
                z += wv.x * gl[k] + wv.y * gl[k + 1] + wv.z * gl[k + 2] + wv.w * gl[k + 3];
            }
            z += b1[tid];
            z1[tid] = z > 0.f ? z : 0.f;
        }
        __syncthreads();

        if (tid < 128) {
            const float* wr = W2 + tid * 128;
            float z = 0.f;
#pragma unroll 8
            for (int k = 0; k < 128; k += 4) {
                float4 wv = *(const float4*)&wr[k];
                z += wv.x * z1[k] + wv.y * z1[k + 1] + wv.z * z1[k + 2] + wv.w * z1[k + 3];
            }
            z += b2[tid];
            z2[tid] = z > 0.f ? z : 0.f;
        }
        __syncthreads();

        if (tid < 64) {
            float p = W3[tid] * z2[tid] + W3[tid + 64] * z2[tid + 64];
#pragma unroll
            for (int off = 32; off; off >>= 1) p += __shfl_down(p, off);
            if (tid == 0) {
                float z = p + b3[0];
                out[g] = (z > 0.f ? z : __expf(z) - 1.f) + 1.5f;
            }
        }
    }
}

// ---------------------------------------------------------------------------
extern "C" void kernel_launch(void* const* d_in, const int* in_sizes, int n_in,
                              void* d_out, int out_size, void* d_ws, size_t ws_size,
                              hipStream_t stream)
{
    const float* x      = (const float*)d_in[0];
    const float* A      = (const float*)d_in[1];
    const float* W_emb  = (const float*)d_in[2];
    const float* gat_W  = (const float*)d_in[3];
    const float* gat_b  = (const float*)d_in[4];
    const float* gat_a  = (const float*)d_in[5];
    const float* fc_W1  = (const float*)d_in[6];
    const float* fc_b1  = (const float*)d_in[7];
    const float* fc_W2  = (const float*)d_in[8];
    const float* fc_b2  = (const float*)d_in[9];
    const float* fc_W3  = (const float*)d_in[10];
    const float* fc_b3  = (const float*)d_in[11];
    float* out = (float*)d_out;

    // workspace (~17.6 MB):
    //   xb bf16 [131072][64]   @ 0          16777216
    //   Wemb_b [256][64]       @ 16777216   32768
    //   Wb [6][256][256] bf16  @ 16809984   786432
    //   ba [6][16] f32         @ 17596416   384
    char* ws = (char*)d_ws;
    __bf16* xb     = (__bf16*)ws;
    __bf16* Wemb_b = (__bf16*)(ws + 16777216);
    __bf16* Wb     = (__bf16*)(ws + 16809984);
    float*  ba     = (float*)(ws + 17596416);

    int conv_total = L_LAYERS * 65536 + L_LAYERS * 16;
    convert_weights<<<(conv_total + 255) / 256, 256, 0, stream>>>(
        W_emb, gat_W, gat_a, gat_b, Wemb_b, Wb, ba);
    convert_x<<<M_FULL * 64 / 256, 256, 0, stream>>>(x, xb);

    mega_gat<<<B_GRAPHS, 256, 0, stream>>>(
        A, xb, Wemb_b, Wb, gat_b, gat_a, ba,
        fc_W1, fc_b1, fc_W2, fc_b2, fc_W3, fc_b3, out);
}